// Round 2
// baseline (1482.753 us; speedup 1.0000x reference)
//
#include <hip/hip_runtime.h>

#define N_NODES 50000
#define N_EDGES 800000
#define NODE_DIM 128
#define EDGE_DIM 64
#define HIDDEN 256
#define K_E 320   // 2*NODE_DIM + EDGE_DIM
#define K_N 192   // NODE_DIM + EDGE_DIM

typedef __attribute__((ext_vector_type(8))) short bf16x8;
typedef __attribute__((ext_vector_type(4))) float f32x4;
typedef unsigned short u16;
typedef unsigned int u32;

__device__ inline u16 f2bf(float f) {
  u32 u = __builtin_bit_cast(u32, f);
  u += 0x7fffu + ((u >> 16) & 1u);
  return (u16)(u >> 16);
}
__device__ inline float bf2f(u16 u) {
  u32 x = ((u32)u) << 16;
  return __builtin_bit_cast(float, x);
}
__device__ inline void st_bf4(u16* p, float4 v) {
  ushort4 r;
  r.x = f2bf(v.x); r.y = f2bf(v.y); r.z = f2bf(v.z); r.w = f2bf(v.w);
  *reinterpret_cast<ushort4*>(p) = r;
}

// ---------------- weight prep: f32 [K][N] -> bf16 [N][K] ----------------
__global__ void prep_weights(const float* __restrict__ We1, const float* __restrict__ We2,
                             const float* __restrict__ Wn1, const float* __restrict__ Wn2,
                             u16* __restrict__ we1t, u16* __restrict__ we2t,
                             u16* __restrict__ wn1t, u16* __restrict__ wn2t) {
  const int stride = gridDim.x * blockDim.x;
  const int tid = blockIdx.x * blockDim.x + threadIdx.x;
  for (int i = tid; i < HIDDEN * K_E; i += stride) {
    int n = i / K_E, k = i % K_E;
    we1t[i] = f2bf(We1[k * HIDDEN + n]);
  }
  for (int i = tid; i < EDGE_DIM * HIDDEN; i += stride) {
    int n = i / HIDDEN, k = i % HIDDEN;
    we2t[i] = f2bf(We2[k * EDGE_DIM + n]);
  }
  for (int i = tid; i < HIDDEN * K_N; i += stride) {
    int n = i / K_N, k = i % K_N;
    wn1t[i] = f2bf(Wn1[k * HIDDEN + n]);
  }
  for (int i = tid; i < NODE_DIM * HIDDEN; i += stride) {
    int n = i / HIDDEN, k = i % HIDDEN;
    wn2t[i] = f2bf(Wn2[k * NODE_DIM + n]);
  }
}

// ---------------- CSR build ----------------
__global__ void hist_kernel(const int* __restrict__ dst, int* __restrict__ hist) {
  int e = blockIdx.x * blockDim.x + threadIdx.x;
  if (e < N_EDGES) atomicAdd(&hist[dst[e]], 1);
}

#define SCAN_T 256
#define SCAN_ITEMS 196  // 256*196 = 50176 >= 50000
__global__ void scan_kernel(const int* __restrict__ hist, int* __restrict__ off,
                            int* __restrict__ cursor) {
  __shared__ int ssum[SCAN_T];
  const int tid = threadIdx.x;
  const int base = tid * SCAN_ITEMS;
  int s = 0;
  for (int i = 0; i < SCAN_ITEMS; ++i) {
    int idx = base + i;
    s += (idx < N_NODES) ? hist[idx] : 0;
  }
  ssum[tid] = s;
  __syncthreads();
  for (int d = 1; d < SCAN_T; d <<= 1) {
    int t = (tid >= d) ? ssum[tid - d] : 0;
    __syncthreads();
    ssum[tid] += t;
    __syncthreads();
  }
  int run = ssum[tid] - s;  // exclusive prefix
  for (int i = 0; i < SCAN_ITEMS; ++i) {
    int idx = base + i;
    if (idx < N_NODES) {
      off[idx] = run;
      cursor[idx] = run;
      run += hist[idx];
    }
  }
  if (tid == SCAN_T - 1) off[N_NODES] = run;
}

__global__ void scatter_kernel(const int* __restrict__ dst, int* __restrict__ cursor,
                               int* __restrict__ rank) {
  int e = blockIdx.x * blockDim.x + threadIdx.x;
  if (e < N_EDGES) rank[e] = atomicAdd(&cursor[dst[e]], 1);
}

// ---------------- edge MLP ----------------
#define SA_E 328  // 320 + 8 pad -> row stride 4 banks, 2-way (free) on b128 reads
#define SH   264  // 256 + 8 pad

__global__ __launch_bounds__(512, 5) void edge_kernel(
    const float* __restrict__ nf, const float* __restrict__ ef,
    const int* __restrict__ src, const int* __restrict__ dst,
    const u16* __restrict__ w1, const float* __restrict__ b1,
    const u16* __restrict__ w2, const float* __restrict__ b2,
    const int* __restrict__ rank, u16* __restrict__ e_upd,
    float* __restrict__ e_sum, float* __restrict__ degf,
    int sorted, float* __restrict__ out_edge)
{
  __shared__ u16 A[64 * SA_E];   // concat tile, later aliased as hidden H
  __shared__ u16 H2[64 * 68];    // layer-2 output bounce (pad 4)
  __shared__ int sidx[64], didx[64], rk[64];
  const int tid = threadIdx.x;
  const int e0 = blockIdx.x * 64;   // N_EDGES % 64 == 0

  if (tid < 64) {
    sidx[tid] = src[e0 + tid];
    didx[tid] = dst[e0 + tid];
    rk[tid] = sorted ? rank[e0 + tid] : 0;
  }
  __syncthreads();

  const float4* nf4 = reinterpret_cast<const float4*>(nf);
  const float4* ef4 = reinterpret_cast<const float4*>(ef);
  float4* oe4 = reinterpret_cast<float4*>(out_edge);

  // stage src halves: cols 0..127 (64 rows x 32 float4)
  #pragma unroll
  for (int p = 0; p < 4; ++p) {
    int i = p * 512 + tid;
    int row = i >> 5, c4 = i & 31;
    float4 v = nf4[(size_t)sidx[row] * 32 + c4];
    st_bf4(&A[row * SA_E + c4 * 4], v);
  }
  // stage edge features: cols 128..191, fused passthrough to out
  #pragma unroll
  for (int p = 0; p < 2; ++p) {
    int i = p * 512 + tid;
    int row = i >> 4, c4 = i & 15;
    size_t g = (size_t)(e0 + row) * 16 + c4;
    float4 v = ef4[g];
    oe4[g] = v;
    st_bf4(&A[row * SA_E + 128 + c4 * 4], v);
  }
  // stage dst halves: cols 192..319
  #pragma unroll
  for (int p = 0; p < 4; ++p) {
    int i = p * 512 + tid;
    int row = i >> 5, c4 = i & 31;
    float4 v = nf4[(size_t)didx[row] * 32 + c4];
    st_bf4(&A[row * SA_E + 192 + c4 * 4], v);
  }
  if (!sorted && tid < 64) degf[didx[tid]] = 1.0f;
  __syncthreads();

  const int wave = tid >> 6, lane = tid & 63;
  const int lr = lane & 15;
  const int lk = (lane >> 4) * 8;

  // layer 1: [64 x 320] @ [320 x 256]; 8 waves = 4 row-tiles x 2 col-halves
  const int wr = wave >> 1;       // row tile (16 rows)
  const int wc = wave & 1;        // col half (128 cols)
  f32x4 acc[8] = {};
  for (int kb = 0; kb < K_E / 32; ++kb) {
    const int ko = kb * 32 + lk;
    bf16x8 a = *reinterpret_cast<const bf16x8*>(&A[(wr * 16 + lr) * SA_E + ko]);
    #pragma unroll
    for (int nt = 0; nt < 8; ++nt) {
      bf16x8 b = *reinterpret_cast<const bf16x8*>(
          &w1[(size_t)(wc * 128 + nt * 16 + lr) * K_E + ko]);
      acc[nt] = __builtin_amdgcn_mfma_f32_16x16x32_bf16(a, b, acc[nt], 0, 0, 0);
    }
  }
  __syncthreads();   // all layer-1 A reads done before aliasing as H

  u16* H = A;
  #pragma unroll
  for (int nt = 0; nt < 8; ++nt) {
    int col = wc * 128 + nt * 16 + lr;
    float bias = b1[col];
    #pragma unroll
    for (int j = 0; j < 4; ++j) {
      int row = wr * 16 + (lane >> 4) * 4 + j;
      float h = acc[nt][j] + bias;
      H[row * SH + col] = f2bf(h > 0.f ? h : 0.f);
    }
  }
  __syncthreads();

  // layer 2: H [64 x 256] @ [256 x 64]; 8 waves = 4 row-tiles x 2 col-halves(32)
  const int r2 = wave >> 1;
  const int c2 = wave & 1;
  f32x4 acc2[2] = {};
  for (int kb = 0; kb < HIDDEN / 32; ++kb) {
    const int ko = kb * 32 + lk;
    bf16x8 a = *reinterpret_cast<const bf16x8*>(&H[(r2 * 16 + lr) * SH + ko]);
    #pragma unroll
    for (int nt = 0; nt < 2; ++nt) {
      bf16x8 b = *reinterpret_cast<const bf16x8*>(
          &w2[(size_t)(c2 * 32 + nt * 16 + lr) * HIDDEN + ko]);
      acc2[nt] = __builtin_amdgcn_mfma_f32_16x16x32_bf16(a, b, acc2[nt], 0, 0, 0);
    }
  }

  if (sorted) {
    // bounce through LDS for coalesced row stores to e_upd[rank]
    #pragma unroll
    for (int nt = 0; nt < 2; ++nt) {
      int col = c2 * 32 + nt * 16 + lr;
      float bias = b2[col];
      #pragma unroll
      for (int j = 0; j < 4; ++j) {
        int row = r2 * 16 + (lane >> 4) * 4 + j;
        H2[row * 68 + col] = f2bf(acc2[nt][j] + bias);
      }
    }
    __syncthreads();
    #pragma unroll
    for (int p = 0; p < 2; ++p) {
      int i = p * 512 + tid;
      int row = i >> 4, c = (i & 15) * 4;
      ushort4 v = *reinterpret_cast<ushort4*>(&H2[row * 68 + c]);
      *reinterpret_cast<ushort4*>(&e_upd[(size_t)rk[row] * 64 + c]) = v;
    }
  } else {
    #pragma unroll
    for (int nt = 0; nt < 2; ++nt) {
      int col = c2 * 32 + nt * 16 + lr;
      float bias = b2[col];
      #pragma unroll
      for (int j = 0; j < 4; ++j) {
        int row = r2 * 16 + (lane >> 4) * 4 + j;
        atomicAdd(&e_sum[(size_t)didx[row] * 64 + col], acc2[nt][j] + bias);
      }
    }
  }
}

// ---------------- node MLP + degree gate ----------------
#define SA_N 200  // 192 + 8 pad

__global__ __launch_bounds__(256) void node_kernel(
    const float* __restrict__ nf,
    const u16* __restrict__ e_upd, const int* __restrict__ off,
    const int* __restrict__ hist,
    const float* __restrict__ e_sum, const float* __restrict__ degf,
    const u16* __restrict__ w1, const float* __restrict__ b1,
    const u16* __restrict__ w2, const float* __restrict__ b2,
    int sorted, float* __restrict__ hout)
{
  __shared__ u16 A[64 * SH];   // staging (stride SA_N) then hidden (stride SH)
  const int tid = threadIdx.x;
  const int n0 = blockIdx.x * 64;

  const float4* nf4 = reinterpret_cast<const float4*>(nf);

  // stage node rows: cols 0..127 (clamped for tail block)
  #pragma unroll
  for (int p = 0; p < 8; ++p) {
    int i = p * 256 + tid;
    int row = i >> 5, c4 = i & 31;
    int rg = min(n0 + row, N_NODES - 1);
    float4 v = nf4[(size_t)rg * 32 + c4];
    st_bf4(&A[row * SA_N + c4 * 4], v);
  }

  if (sorted) {
    // CSR gather-sum of sorted messages: 16 groups of 16 lanes, 4 rows each
    const int g = tid >> 4, l16 = tid & 15;
    for (int row = g; row < 64; row += 16) {
      int n = n0 + row;
      float4 acc = {0.f, 0.f, 0.f, 0.f};
      if (n < N_NODES) {
        int s0 = off[n], s1 = off[n + 1];
        for (int s = s0; s < s1; ++s) {
          ushort4 v = *reinterpret_cast<const ushort4*>(&e_upd[(size_t)s * 64 + l16 * 4]);
          acc.x += bf2f(v.x); acc.y += bf2f(v.y);
          acc.z += bf2f(v.z); acc.w += bf2f(v.w);
        }
      }
      st_bf4(&A[row * SA_N + 128 + l16 * 4], acc);
    }
  } else {
    const float4* es4 = reinterpret_cast<const float4*>(e_sum);
    #pragma unroll
    for (int p = 0; p < 4; ++p) {
      int i = p * 256 + tid;
      int row = i >> 4, c4 = i & 15;
      int rg = min(n0 + row, N_NODES - 1);
      float4 v = es4[(size_t)rg * 16 + c4];
      st_bf4(&A[row * SA_N + 128 + c4 * 4], v);
    }
  }
  __syncthreads();

  const int wave = tid >> 6, lane = tid & 63;
  const int lr = lane & 15;
  const int lk = (lane >> 4) * 8;

  // layer 1: [64 x 192] @ [192 x 256]; wave owns 64 cols
  f32x4 acc[4][4] = {};
  for (int kb = 0; kb < K_N / 32; ++kb) {
    const int ko = kb * 32 + lk;
    bf16x8 a[4], b[4];
    #pragma unroll
    for (int mt = 0; mt < 4; ++mt)
      a[mt] = *reinterpret_cast<const bf16x8*>(&A[(mt * 16 + lr) * SA_N + ko]);
    #pragma unroll
    for (int nt = 0; nt < 4; ++nt)
      b[nt] = *reinterpret_cast<const bf16x8*>(&w1[(size_t)(wave * 64 + nt * 16 + lr) * K_N + ko]);
    #pragma unroll
    for (int mt = 0; mt < 4; ++mt)
      #pragma unroll
      for (int nt = 0; nt < 4; ++nt)
        acc[mt][nt] = __builtin_amdgcn_mfma_f32_16x16x32_bf16(a[mt], b[nt], acc[mt][nt], 0, 0, 0);
  }
  __syncthreads();

  u16* H = A;
  #pragma unroll
  for (int mt = 0; mt < 4; ++mt)
    #pragma unroll
    for (int nt = 0; nt < 4; ++nt) {
      int col = wave * 64 + nt * 16 + lr;
      float bias = b1[col];
      #pragma unroll
      for (int j = 0; j < 4; ++j) {
        int row = mt * 16 + (lane >> 4) * 4 + j;
        float h = acc[mt][nt][j] + bias;
        H[row * SH + col] = f2bf(h > 0.f ? h : 0.f);
      }
    }
  __syncthreads();

  // layer 2: H [64 x 256] @ [256 x 128]; wave owns 16 rows, all 128 cols
  f32x4 acc2[8] = {};
  for (int kb = 0; kb < HIDDEN / 32; ++kb) {
    const int ko = kb * 32 + lk;
    bf16x8 a = *reinterpret_cast<const bf16x8*>(&H[(wave * 16 + lr) * SH + ko]);
    #pragma unroll
    for (int nt = 0; nt < 8; ++nt) {
      bf16x8 b = *reinterpret_cast<const bf16x8*>(&w2[(size_t)(nt * 16 + lr) * HIDDEN + ko]);
      acc2[nt] = __builtin_amdgcn_mfma_f32_16x16x32_bf16(a, b, acc2[nt], 0, 0, 0);
    }
  }
  #pragma unroll
  for (int nt = 0; nt < 8; ++nt) {
    int col = nt * 16 + lr;
    float bias = b2[col];
    #pragma unroll
    for (int j = 0; j < 4; ++j) {
      int row = wave * 16 + (lane >> 4) * 4 + j;
      int rg = n0 + row;
      if (rg < N_NODES) {
        bool has_in = sorted ? (hist[rg] != 0) : (degf[rg] > 0.f);
        float v = acc2[nt][j] + bias;
        hout[(size_t)rg * NODE_DIM + col] =
            has_in ? v : nf[(size_t)rg * NODE_DIM + col];
      }
    }
  }
}

// ---------------- launcher ----------------
extern "C" void kernel_launch(void* const* d_in, const int* in_sizes, int n_in,
                              void* d_out, int out_size, void* d_ws, size_t ws_size,
                              hipStream_t stream) {
  const float* nf  = (const float*)d_in[0];
  const float* ef  = (const float*)d_in[1];
  const int*   src = (const int*)d_in[2];
  const int*   dst = (const int*)d_in[3];
  const float* We1 = (const float*)d_in[4];
  const float* be1 = (const float*)d_in[5];
  const float* We2 = (const float*)d_in[6];
  const float* be2 = (const float*)d_in[7];
  const float* Wn1 = (const float*)d_in[8];
  const float* bn1 = (const float*)d_in[9];
  const float* Wn2 = (const float*)d_in[10];
  const float* bn2 = (const float*)d_in[11];

  float* hout = (float*)d_out;
  float* out_edge = hout + (size_t)N_NODES * NODE_DIM;

  char* ws = (char*)d_ws;

  // sorted-CSR layout needs ~106.6 MB of workspace
  const size_t NEED_SORTED = 106560464;
  int sorted = (ws_size >= NEED_SORTED) ? 1 : 0;

  if (sorted) {
    int* hist    = (int*)ws;                       // 200,000 B
    int* off     = (int*)(ws + 200000);            // 200,004 B
    int* cursor  = (int*)(ws + 400016);            // 200,000 B
    int* rank    = (int*)(ws + 600016);            // 3,200,000 B
    u16* e_upd   = (u16*)(ws + 3800016);           // 102,400,000 B
    u16* we1t    = (u16*)(ws + 106200016);         // 163,840 B
    u16* we2t    = (u16*)(ws + 106363856);         // 32,768 B
    u16* wn1t    = (u16*)(ws + 106396624);         // 98,304 B
    u16* wn2t    = (u16*)(ws + 106494928);         // 65,536 B

    hipMemsetAsync(hist, 0, 200000, stream);
    prep_weights<<<128, 256, 0, stream>>>(We1, We2, Wn1, Wn2, we1t, we2t, wn1t, wn2t);
    hist_kernel<<<(N_EDGES + 255) / 256, 256, 0, stream>>>(dst, hist);
    scan_kernel<<<1, SCAN_T, 0, stream>>>(hist, off, cursor);
    scatter_kernel<<<(N_EDGES + 255) / 256, 256, 0, stream>>>(dst, cursor, rank);
    edge_kernel<<<N_EDGES / 64, 512, 0, stream>>>(nf, ef, src, dst, we1t, be1, we2t, be2,
                                                  rank, e_upd, nullptr, nullptr, 1, out_edge);
    node_kernel<<<(N_NODES + 63) / 64, 256, 0, stream>>>(nf, e_upd, off, hist,
                                                         nullptr, nullptr,
                                                         wn1t, bn1, wn2t, bn2, 1, hout);
  } else {
    float* e_sum = (float*)ws;                     // 12,800,000 B
    float* degf  = (float*)(ws + 12800000);        // 200,000 B
    u16*  we1t   = (u16*)(ws + 13000000);
    u16*  we2t   = (u16*)(ws + 13163840);
    u16*  wn1t   = (u16*)(ws + 13196608);
    u16*  wn2t   = (u16*)(ws + 13294912);

    hipMemsetAsync(ws, 0, 13000000, stream);
    prep_weights<<<128, 256, 0, stream>>>(We1, We2, Wn1, Wn2, we1t, we2t, wn1t, wn2t);
    edge_kernel<<<N_EDGES / 64, 512, 0, stream>>>(nf, ef, src, dst, we1t, be1, we2t, be2,
                                                  nullptr, nullptr, e_sum, degf, 0, out_edge);
    node_kernel<<<(N_NODES + 63) / 64, 256, 0, stream>>>(nf, nullptr, nullptr, nullptr,
                                                         e_sum, degf,
                                                         wn1t, bn1, wn2t, bn2, 0, hout);
  }
}

// Round 4
// 693.631 us; speedup vs baseline: 2.1377x; 2.1377x over previous
//
#include <hip/hip_runtime.h>

#define N_NODES 50000
#define N_EDGES 800000
#define NODE_DIM 128
#define EDGE_DIM 64
#define HIDDEN 256
#define K_E 320   // 2*NODE_DIM + EDGE_DIM
#define K_N 192   // NODE_DIM + EDGE_DIM

typedef __attribute__((ext_vector_type(8))) short bf16x8;
typedef __attribute__((ext_vector_type(4))) float f32x4;
typedef unsigned short u16;
typedef unsigned int u32;

#define MFMA __builtin_amdgcn_mfma_f32_16x16x32_bf16

__device__ inline u16 f2bf(float f) {
  u32 u = __builtin_bit_cast(u32, f);
  u += 0x7fffu + ((u >> 16) & 1u);
  return (u16)(u >> 16);
}
__device__ inline float bf2f(u16 u) {
  u32 x = ((u32)u) << 16;
  return __builtin_bit_cast(float, x);
}
__device__ inline u32 pack2(float a, float b) {
  return (u32)f2bf(a) | ((u32)f2bf(b) << 16);
}
__device__ inline void st_bf4(u16* p, float4 v) {
  ushort4 r;
  r.x = f2bf(v.x); r.y = f2bf(v.y); r.z = f2bf(v.z); r.w = f2bf(v.w);
  *reinterpret_cast<ushort4*>(p) = r;
}

// ---------------- weight prep ----------------
// fragfmt=1: w1x frag-order [kb][t][g][lr][jj] (A-operand, hidden-as-m);
//            w2x frag-order [kb2][t2][g][lr][jj] (A-operand, out-as-m); nfb written.
// fragfmt=0: w1x row-major [256][320]; w2x row-major [64][256]. (fallback)
__global__ void prep_weights(const float* __restrict__ We1, const float* __restrict__ We2,
                             const float* __restrict__ Wn1, const float* __restrict__ Wn2,
                             const float* __restrict__ nf,
                             u16* __restrict__ w1x, u16* __restrict__ w2x,
                             u16* __restrict__ wn1t, u16* __restrict__ wn2t,
                             u16* __restrict__ nfb, int fragfmt) {
  const int stride = gridDim.x * blockDim.x;
  const int tid = blockIdx.x * blockDim.x + threadIdx.x;
  for (int i = tid; i < HIDDEN * K_E; i += stride) {
    int h, k;
    if (fragfmt) {
      int jj = i & 7, lr = (i >> 3) & 15, g = (i >> 7) & 3, t = (i >> 9) & 15, kb = i >> 13;
      h = t * 16 + lr; k = kb * 32 + g * 8 + jj;
    } else { h = i / K_E; k = i % K_E; }
    w1x[i] = f2bf(We1[k * HIDDEN + h]);
  }
  for (int i = tid; i < EDGE_DIM * HIDDEN; i += stride) {
    int n, k;
    if (fragfmt) {
      int jj = i & 7, lr = (i >> 3) & 15, g = (i >> 7) & 3, t2 = (i >> 9) & 3, kb2 = (i >> 11) & 7;
      n = t2 * 16 + lr; k = kb2 * 32 + g * 8 + jj;
    } else { n = i / HIDDEN; k = i % HIDDEN; }
    w2x[i] = f2bf(We2[k * EDGE_DIM + n]);
  }
  for (int i = tid; i < HIDDEN * K_N; i += stride) {
    int n = i / K_N, k = i % K_N;
    wn1t[i] = f2bf(Wn1[k * HIDDEN + n]);
  }
  for (int i = tid; i < NODE_DIM * HIDDEN; i += stride) {
    int n = i / HIDDEN, k = i % HIDDEN;
    wn2t[i] = f2bf(Wn2[k * NODE_DIM + n]);
  }
  if (fragfmt) {
    const float4* nf4 = reinterpret_cast<const float4*>(nf);
    for (int i = tid; i < N_NODES * NODE_DIM / 4; i += stride)
      st_bf4(&nfb[i * 4], nf4[i]);
  }
}

// ---------------- CSR build ----------------
__global__ void hist_kernel(const int* __restrict__ dst, int* __restrict__ hist) {
  int e = blockIdx.x * blockDim.x + threadIdx.x;
  if (e < N_EDGES) atomicAdd(&hist[dst[e]], 1);
}

#define SCAN_T 256
#define SCAN_ITEMS 196  // 256*196 = 50176 >= 50000
__global__ void scan_kernel(const int* __restrict__ hist, int* __restrict__ off,
                            int* __restrict__ cursor) {
  __shared__ int ssum[SCAN_T];
  const int tid = threadIdx.x;
  const int base = tid * SCAN_ITEMS;
  int s = 0;
  for (int i = 0; i < SCAN_ITEMS; ++i) {
    int idx = base + i;
    s += (idx < N_NODES) ? hist[idx] : 0;
  }
  ssum[tid] = s;
  __syncthreads();
  for (int d = 1; d < SCAN_T; d <<= 1) {
    int t = (tid >= d) ? ssum[tid - d] : 0;
    __syncthreads();
    ssum[tid] += t;
    __syncthreads();
  }
  int run = ssum[tid] - s;  // exclusive prefix
  for (int i = 0; i < SCAN_ITEMS; ++i) {
    int idx = base + i;
    if (idx < N_NODES) {
      off[idx] = run;
      cursor[idx] = run;
      run += hist[idx];
    }
  }
  if (tid == SCAN_T - 1) off[N_NODES] = run;
}

__global__ void scatter_kernel(const int* __restrict__ dst, int* __restrict__ cursor,
                               int* __restrict__ rank) {
  int e = blockIdx.x * blockDim.x + threadIdx.x;
  if (e < N_EDGES) rank[e] = atomicAdd(&cursor[dst[e]], 1);
}

// ---------------- edge MLP v3b: operand-swapped, register-resident ----------------
// 512 thr = 8 waves; 16 edges/wave, 128 edges/block. LDS 32KB:
// phase 1: W1 kb-tile double-buffer (2x16KB).
// phase 2: per-wave 4KB H-bounce slot, layer 2 split into two k-halves
//          (hidden 0..127 then 128..255) so each half fits the slot exactly.
__global__ __launch_bounds__(512, 2) void edge_mlp(
    const u16* __restrict__ nfb, const float* __restrict__ ef,
    const int* __restrict__ src, const int* __restrict__ dst,
    const u16* __restrict__ w1f, const float* __restrict__ b1,
    const u16* __restrict__ w2f, const float* __restrict__ b2,
    const int* __restrict__ rank, u16* __restrict__ e_upd,
    float* __restrict__ out_edge)
{
  __shared__ u16 W[16384];   // 32KB

  const int tid = threadIdx.x;
  const int wv = tid >> 6, lane = tid & 63;
  const int er = lane & 15;      // edge index within wave tile (m-col of D)
  const int g  = lane >> 4;      // k-group
  const int e0 = blockIdx.x * 128;
  const int eg = e0 + wv * 16 + er;

  // ---- fused edge-feature passthrough (fp32), fully coalesced ----
  {
    const float4* ef4 = reinterpret_cast<const float4*>(ef);
    float4* oe4 = reinterpret_cast<float4*>(out_edge);
    #pragma unroll
    for (int p = 0; p < 4; ++p) {
      size_t i = (size_t)e0 * 16 + p * 512 + tid;
      oe4[i] = ef4[i];
    }
  }

  // ---- gather edge concat features into B-operand fragments ----
  const int si = src[eg] << 7;   // *NODE_DIM
  const int di = dst[eg] << 7;
  bf16x8 efr[10];
  #pragma unroll
  for (int kb = 0; kb < 4; ++kb)
    efr[kb] = *reinterpret_cast<const bf16x8*>(nfb + si + kb * 32 + g * 8);
  #pragma unroll
  for (int kb = 0; kb < 2; ++kb) {
    const float* ep = ef + (size_t)eg * 64 + kb * 32 + g * 8;
    float4 lo = *reinterpret_cast<const float4*>(ep);
    float4 hi = *reinterpret_cast<const float4*>(ep + 4);
    bf16x8 v;
    v[0] = (short)f2bf(lo.x); v[1] = (short)f2bf(lo.y);
    v[2] = (short)f2bf(lo.z); v[3] = (short)f2bf(lo.w);
    v[4] = (short)f2bf(hi.x); v[5] = (short)f2bf(hi.y);
    v[6] = (short)f2bf(hi.z); v[7] = (short)f2bf(hi.w);
    efr[4 + kb] = v;
  }
  #pragma unroll
  for (int kb = 0; kb < 4; ++kb)
    efr[6 + kb] = *reinterpret_cast<const bf16x8*>(nfb + di + kb * 32 + g * 8);

  // ---- layer-1 acc init with bias: acc[t][j] = b1[t*16 + g*4 + j] ----
  f32x4 acc[16];
  #pragma unroll
  for (int t = 0; t < 16; ++t)
    acc[t] = *reinterpret_cast<const f32x4*>(b1 + t * 16 + g * 4);

  // ---- layer 1: H'[hidden][edge] = W1(A) x edges(B), W1 LDS double-buffered ----
  const uint4* w1s4 = reinterpret_cast<const uint4*>(w1f);
  {
    uint4* d4 = reinterpret_cast<uint4*>(W);
    d4[tid] = w1s4[tid];
    d4[tid + 512] = w1s4[tid + 512];
  }
  __syncthreads();

  #pragma unroll
  for (int kb = 0; kb < 10; ++kb) {
    uint4 nv0, nv1;
    if (kb < 9) {   // issue next-tile loads early (hide L2 latency under MFMAs)
      nv0 = w1s4[(kb + 1) * 1024 + tid];
      nv1 = w1s4[(kb + 1) * 1024 + tid + 512];
    }
    const u16* Wc = W + (kb & 1) * 8192;
    #pragma unroll
    for (int t = 0; t < 16; ++t) {
      bf16x8 wf = *reinterpret_cast<const bf16x8*>(Wc + ((t * 4 + g) * 16 + er) * 8);
      acc[t] = MFMA(wf, efr[kb], acc[t], 0, 0, 0);
    }
    if (kb < 9) {
      uint4* d4 = reinterpret_cast<uint4*>(W + ((kb + 1) & 1) * 8192);
      d4[tid] = nv0;
      d4[tid + 512] = nv1;
    }
    __syncthreads();
  }

  // ---- per-wave 4KB H bounce + layer 2 (operand-swapped), two k-halves ----
  u16* hb = W + wv * 2048;   // 2048 u16 = 4KB per-wave slot

  // layer-2 acc init with bias: acc2[t2][j] = b2[t2*16 + g*4 + j]
  f32x4 acc2[4];
  #pragma unroll
  for (int t2 = 0; t2 < 4; ++t2)
    acc2[t2] = *reinterpret_cast<const f32x4*>(b2 + t2 * 16 + g * 4);

  #pragma unroll
  for (int ph = 0; ph < 2; ++ph) {
    // write H half: t = ph*8 .. ph*8+7 (hidden ph*128 .. ph*128+127)
    #pragma unroll
    for (int tt = 0; tt < 8; ++tt) {
      int t = ph * 8 + tt;
      u32 pk0 = pack2(fmaxf(acc[t][0], 0.f), fmaxf(acc[t][1], 0.f));
      u32 pk1 = pack2(fmaxf(acc[t][2], 0.f), fmaxf(acc[t][3], 0.f));
      int aloc = tt >> 1;                  // local kb2 (0..3)
      int gp = (t & 1) * 2 + (g >> 1);
      int unit = (aloc * 4 + gp) * 16 + er;
      uint2 pv; pv.x = pk0; pv.y = pk1;
      *reinterpret_cast<uint2*>(hb + unit * 8 + (g & 1) * 4) = pv;
    }

    // consume: kb2 = ph*4 .. ph*4+3
    #pragma unroll
    for (int kl = 0; kl < 4; ++kl) {
      int kb2 = ph * 4 + kl;
      bf16x8 hf = *reinterpret_cast<const bf16x8*>(hb + ((kl * 4 + g) * 16 + er) * 8);
      #pragma unroll
      for (int t2 = 0; t2 < 4; ++t2) {
        bf16x8 wf2 = *reinterpret_cast<const bf16x8*>(
            w2f + (((kb2 * 4 + t2) * 4 + g) * 16 + er) * 8);
        acc2[t2] = MFMA(wf2, hf, acc2[t2], 0, 0, 0);
      }
    }
  }

  // ---- bounce C' tile [16 edges][64 out] (stride 72 u16) for coalesced scatter ----
  #pragma unroll
  for (int t2 = 0; t2 < 4; ++t2) {
    uint2 pv;
    pv.x = pack2(acc2[t2][0], acc2[t2][1]);
    pv.y = pack2(acc2[t2][2], acc2[t2][3]);
    *reinterpret_cast<uint2*>(hb + er * 72 + t2 * 16 + g * 4) = pv;
  }

  // scatter: 4 lanes per edge row, 32B each -> e_upd[rank[e]]
  {
    int r = lane >> 2, q = lane & 3;
    int rk = rank[e0 + wv * 16 + r];
    uint4 c0 = *reinterpret_cast<const uint4*>(hb + r * 72 + q * 16);
    uint4 c1 = *reinterpret_cast<const uint4*>(hb + r * 72 + q * 16 + 8);
    uint4* dp = reinterpret_cast<uint4*>(e_upd + (size_t)rk * 64 + q * 16);
    dp[0] = c0;
    dp[1] = c1;
  }
}

// ---------------- edge MLP fallback (R2 structure, sorted path only) ----------------
#define SA_E 328
#define SH   264

__global__ __launch_bounds__(512) void edge_old(
    const float* __restrict__ nf, const float* __restrict__ ef,
    const int* __restrict__ src, const int* __restrict__ dst,
    const u16* __restrict__ w1, const float* __restrict__ b1,
    const u16* __restrict__ w2, const float* __restrict__ b2,
    const int* __restrict__ rank, u16* __restrict__ e_upd,
    float* __restrict__ out_edge)
{
  __shared__ u16 A[64 * SA_E];
  __shared__ u16 H2[64 * 68];
  __shared__ int sidx[64], didx[64], rk[64];
  const int tid = threadIdx.x;
  const int e0 = blockIdx.x * 64;

  if (tid < 64) {
    sidx[tid] = src[e0 + tid];
    didx[tid] = dst[e0 + tid];
    rk[tid] = rank[e0 + tid];
  }
  __syncthreads();

  const float4* nf4 = reinterpret_cast<const float4*>(nf);
  const float4* ef4 = reinterpret_cast<const float4*>(ef);
  float4* oe4 = reinterpret_cast<float4*>(out_edge);

  #pragma unroll
  for (int p = 0; p < 4; ++p) {
    int i = p * 512 + tid;
    int row = i >> 5, c4 = i & 31;
    float4 v = nf4[(size_t)sidx[row] * 32 + c4];
    st_bf4(&A[row * SA_E + c4 * 4], v);
  }
  #pragma unroll
  for (int p = 0; p < 2; ++p) {
    int i = p * 512 + tid;
    int row = i >> 4, c4 = i & 15;
    size_t gidx = (size_t)(e0 + row) * 16 + c4;
    float4 v = ef4[gidx];
    oe4[gidx] = v;
    st_bf4(&A[row * SA_E + 128 + c4 * 4], v);
  }
  #pragma unroll
  for (int p = 0; p < 4; ++p) {
    int i = p * 512 + tid;
    int row = i >> 5, c4 = i & 31;
    float4 v = nf4[(size_t)didx[row] * 32 + c4];
    st_bf4(&A[row * SA_E + 192 + c4 * 4], v);
  }
  __syncthreads();

  const int wave = tid >> 6, lane = tid & 63;
  const int lr = lane & 15;
  const int lk = (lane >> 4) * 8;

  const int wr = wave >> 1;
  const int wc = wave & 1;
  f32x4 acc[8] = {};
  for (int kb = 0; kb < K_E / 32; ++kb) {
    const int ko = kb * 32 + lk;
    bf16x8 a = *reinterpret_cast<const bf16x8*>(&A[(wr * 16 + lr) * SA_E + ko]);
    #pragma unroll
    for (int nt = 0; nt < 8; ++nt) {
      bf16x8 b = *reinterpret_cast<const bf16x8*>(
          &w1[(size_t)(wc * 128 + nt * 16 + lr) * K_E + ko]);
      acc[nt] = MFMA(a, b, acc[nt], 0, 0, 0);
    }
  }
  __syncthreads();

  u16* H = A;
  #pragma unroll
  for (int nt = 0; nt < 8; ++nt) {
    int col = wc * 128 + nt * 16 + lr;
    float bias = b1[col];
    #pragma unroll
    for (int j = 0; j < 4; ++j) {
      int row = wr * 16 + (lane >> 4) * 4 + j;
      float h = acc[nt][j] + bias;
      H[row * SH + col] = f2bf(h > 0.f ? h : 0.f);
    }
  }
  __syncthreads();

  const int r2 = wave >> 1;
  const int c2 = wave & 1;
  f32x4 acc2[2] = {};
  for (int kb = 0; kb < HIDDEN / 32; ++kb) {
    const int ko = kb * 32 + lk;
    bf16x8 a = *reinterpret_cast<const bf16x8*>(&H[(r2 * 16 + lr) * SH + ko]);
    #pragma unroll
    for (int nt = 0; nt < 2; ++nt) {
      bf16x8 b = *reinterpret_cast<const bf16x8*>(
          &w2[(size_t)(c2 * 32 + nt * 16 + lr) * HIDDEN + ko]);
      acc2[nt] = MFMA(a, b, acc2[nt], 0, 0, 0);
    }
  }

  #pragma unroll
  for (int nt = 0; nt < 2; ++nt) {
    int col = c2 * 32 + nt * 16 + lr;
    float bias = b2[col];
    #pragma unroll
    for (int j = 0; j < 4; ++j) {
      int row = r2 * 16 + (lane >> 4) * 4 + j;
      H2[row * 68 + col] = f2bf(acc2[nt][j] + bias);
    }
  }
  __syncthreads();
  #pragma unroll
  for (int p = 0; p < 2; ++p) {
    int i = p * 512 + tid;
    int row = i >> 4, c = (i & 15) * 4;
    ushort4 v = *reinterpret_cast<ushort4*>(&H2[row * 68 + c]);
    *reinterpret_cast<ushort4*>(&e_upd[(size_t)rk[row] * 64 + c]) = v;
  }
}

// ---------------- node MLP + degree gate (sorted/CSR) ----------------
#define SA_N 200

__global__ __launch_bounds__(256) void node_kernel(
    const float* __restrict__ nf,
    const u16* __restrict__ e_upd, const int* __restrict__ off,
    const int* __restrict__ hist,
    const u16* __restrict__ w1, const float* __restrict__ b1,
    const u16* __restrict__ w2, const float* __restrict__ b2,
    float* __restrict__ hout)
{
  __shared__ u16 A[64 * SH];
  const int tid = threadIdx.x;
  const int n0 = blockIdx.x * 64;

  const float4* nf4 = reinterpret_cast<const float4*>(nf);

  #pragma unroll
  for (int p = 0; p < 8; ++p) {
    int i = p * 256 + tid;
    int row = i >> 5, c4 = i & 31;
    int rg = min(n0 + row, N_NODES - 1);
    float4 v = nf4[(size_t)rg * 32 + c4];
    st_bf4(&A[row * SA_N + c4 * 4], v);
  }

  {
    const int gg = tid >> 4, l16 = tid & 15;
    for (int row = gg; row < 64; row += 16) {
      int n = n0 + row;
      float4 accv = {0.f, 0.f, 0.f, 0.f};
      if (n < N_NODES) {
        int s0 = off[n], s1 = off[n + 1];
        for (int s = s0; s < s1; ++s) {
          ushort4 v = *reinterpret_cast<const ushort4*>(&e_upd[(size_t)s * 64 + l16 * 4]);
          accv.x += bf2f(v.x); accv.y += bf2f(v.y);
          accv.z += bf2f(v.z); accv.w += bf2f(v.w);
        }
      }
      st_bf4(&A[row * SA_N + 128 + l16 * 4], accv);
    }
  }
  __syncthreads();

  const int wave = tid >> 6, lane = tid & 63;
  const int lr = lane & 15;
  const int lk = (lane >> 4) * 8;

  f32x4 acc[4][4] = {};
  for (int kb = 0; kb < K_N / 32; ++kb) {
    const int ko = kb * 32 + lk;
    bf16x8 a[4], b[4];
    #pragma unroll
    for (int mt = 0; mt < 4; ++mt)
      a[mt] = *reinterpret_cast<const bf16x8*>(&A[(mt * 16 + lr) * SA_N + ko]);
    #pragma unroll
    for (int nt = 0; nt < 4; ++nt)
      b[nt] = *reinterpret_cast<const bf16x8*>(&w1[(size_t)(wave * 64 + nt * 16 + lr) * K_N + ko]);
    #pragma unroll
    for (int mt = 0; mt < 4; ++mt)
      #pragma unroll
      for (int nt = 0; nt < 4; ++nt)
        acc[mt][nt] = MFMA(a[mt], b[nt], acc[mt][nt], 0, 0, 0);
  }
  __syncthreads();

  u16* H = A;
  #pragma unroll
  for (int mt = 0; mt < 4; ++mt)
    #pragma unroll
    for (int nt = 0; nt < 4; ++nt) {
      int col = wave * 64 + nt * 16 + lr;
      float bias = b1[col];
      #pragma unroll
      for (int j = 0; j < 4; ++j) {
        int row = mt * 16 + (lane >> 4) * 4 + j;
        float h = acc[mt][nt][j] + bias;
        H[row * SH + col] = f2bf(h > 0.f ? h : 0.f);
      }
    }
  __syncthreads();

  f32x4 acc2[8] = {};
  for (int kb = 0; kb < HIDDEN / 32; ++kb) {
    const int ko = kb * 32 + lk;
    bf16x8 a = *reinterpret_cast<const bf16x8*>(&H[(wave * 16 + lr) * SH + ko]);
    #pragma unroll
    for (int nt = 0; nt < 8; ++nt) {
      bf16x8 b = *reinterpret_cast<const bf16x8*>(&w2[(size_t)(nt * 16 + lr) * HIDDEN + ko]);
      acc2[nt] = MFMA(a, b, acc2[nt], 0, 0, 0);
    }
  }
  #pragma unroll
  for (int nt = 0; nt < 8; ++nt) {
    int col = nt * 16 + lr;
    float bias = b2[col];
    #pragma unroll
    for (int j = 0; j < 4; ++j) {
      int row = wave * 16 + (lane >> 4) * 4 + j;
      int rg = n0 + row;
      if (rg < N_NODES) {
        float v = acc2[nt][j] + bias;
        hout[(size_t)rg * NODE_DIM + col] =
            (hist[rg] != 0) ? v : nf[(size_t)rg * NODE_DIM + col];
      }
    }
  }
}

// ---------------- launcher ----------------
extern "C" void kernel_launch(void* const* d_in, const int* in_sizes, int n_in,
                              void* d_out, int out_size, void* d_ws, size_t ws_size,
                              hipStream_t stream) {
  const float* nf  = (const float*)d_in[0];
  const float* ef  = (const float*)d_in[1];
  const int*   src = (const int*)d_in[2];
  const int*   dst = (const int*)d_in[3];
  const float* We1 = (const float*)d_in[4];
  const float* be1 = (const float*)d_in[5];
  const float* We2 = (const float*)d_in[6];
  const float* be2 = (const float*)d_in[7];
  const float* Wn1 = (const float*)d_in[8];
  const float* bn1 = (const float*)d_in[9];
  const float* Wn2 = (const float*)d_in[10];
  const float* bn2 = (const float*)d_in[11];

  float* hout = (float*)d_out;
  float* out_edge = hout + (size_t)N_NODES * NODE_DIM;

  char* ws = (char*)d_ws;
  int* hist    = (int*)ws;                       // 200,000 B
  int* off     = (int*)(ws + 200000);            // 200,004 B
  int* cursor  = (int*)(ws + 400016);            // 200,000 B
  int* rank    = (int*)(ws + 600016);            // 3,200,000 B
  u16* e_upd   = (u16*)(ws + 3800016);           // 102,400,000 B
  u16* w1x     = (u16*)(ws + 106200016);         // 163,840 B
  u16* w2x     = (u16*)(ws + 106363856);         // 32,768 B
  u16* wn1t    = (u16*)(ws + 106396624);         // 98,304 B
  u16* wn2t    = (u16*)(ws + 106494928);         // 65,536 B
  u16* nfb     = (u16*)(ws + 106560464);         // 12,800,000 B
  const size_t NEED_NEW = 119360464;
  int fragfmt = (ws_size >= NEED_NEW) ? 1 : 0;

  hipMemsetAsync(hist, 0, 200000, stream);
  prep_weights<<<512, 256, 0, stream>>>(We1, We2, Wn1, Wn2, nf, w1x, w2x, wn1t, wn2t,
                                        fragfmt ? nfb : wn2t /*unused*/, fragfmt);
  hist_kernel<<<(N_EDGES + 255) / 256, 256, 0, stream>>>(dst, hist);
  scan_kernel<<<1, SCAN_T, 0, stream>>>(hist, off, cursor);
  scatter_kernel<<<(N_EDGES + 255) / 256, 256, 0, stream>>>(dst, cursor, rank);

  if (fragfmt) {
    edge_mlp<<<N_EDGES / 128, 512, 0, stream>>>(nfb, ef, src, dst, w1x, be1, w2x, be2,
                                                rank, e_upd, out_edge);
  } else {
    edge_old<<<N_EDGES / 64, 512, 0, stream>>>(nf, ef, src, dst, w1x, be1, w2x, be2,
                                               rank, e_upd, out_edge);
  }
  node_kernel<<<(N_NODES + 63) / 64, 256, 0, stream>>>(nf, e_upd, off, hist,
                                                       wn1t, bn1, wn2t, bn2, hout);
}